// Round 1
// baseline (926.204 us; speedup 1.0000x reference)
//
#include <hip/hip_runtime.h>
#include <float.h>

// DGCNN_Grouper forward on MI355X.
// B=8, N=2048, K=16. All fp32.
// Stages: in_trans -> [knn1, edge1] ; fps1 -> fps2 (coords only, overlapped)
//         -> knn2/edge2 -> knn3/edge3 -> knn4/edge4 -> (coor_q2, f4)

#define DI __device__ __forceinline__
DI float f_add(float a, float b) { return __fadd_rn(a, b); }
DI float f_sub(float a, float b) { return __fsub_rn(a, b); }
DI float f_mul(float a, float b) { return __fmul_rn(a, b); }

// ---------------------------------------------------------------------------
// kNN: for each query, 16 smallest d2 (stable ties -> lower index), d2 computed
// exactly as reference: (|q|^2 + |r|^2) - 2*dot, each op individually rounded.
// One wave per query; candidates staged in LDS (shared by 4 waves per block).
// ---------------------------------------------------------------------------
template<int NK>
DI void knn_body(const float* __restrict__ cq, int Nq,
                 const float* __restrict__ ck, int* __restrict__ out,
                 int b, int qbase, float* smem)
{
  constexpr int CPL = NK / 64;  // candidates per lane
  float* xs = smem;
  float* ys = smem + NK;
  float* zs = smem + 2*NK;
  float* rr = smem + 3*NK;
  const int tid = threadIdx.x;
  for (int i = tid; i < NK; i += 256) {
    float a  = ck[((size_t)b*3 + 0)*NK + i];
    float bb = ck[((size_t)b*3 + 1)*NK + i];
    float c  = ck[((size_t)b*3 + 2)*NK + i];
    xs[i] = a; ys[i] = bb; zs[i] = c;
    rr[i] = f_add(f_add(f_mul(a,a), f_mul(bb,bb)), f_mul(c,c));
  }
  __syncthreads();
  const int lane = tid & 63, w = tid >> 6;
  const int q = qbase + w;
  if (q >= Nq) return;
  float qx = cq[((size_t)b*3 + 0)*Nq + q];
  float qy = cq[((size_t)b*3 + 1)*Nq + q];
  float qz = cq[((size_t)b*3 + 2)*Nq + q];
  float qq = f_add(f_add(f_mul(qx,qx), f_mul(qy,qy)), f_mul(qz,qz));
  float v[CPL];
  #pragma unroll
  for (int j = 0; j < CPL; ++j) {
    int c = j*64 + lane;
    float dot = f_add(f_add(f_mul(qx,xs[c]), f_mul(qy,ys[c])), f_mul(qz,zs[c]));
    v[j] = f_sub(f_add(qq, rr[c]), f_mul(2.0f, dot));
  }
  unsigned mask = (CPL >= 32) ? 0xFFFFFFFFu : ((1u << CPL) - 1u);
  for (int r = 0; r < 16; ++r) {
    float bv = FLT_MAX; int bc = 0x7FFFFFFF;
    #pragma unroll
    for (int j = 0; j < CPL; ++j) {
      float vj = ((mask >> j) & 1u) ? v[j] : FLT_MAX;
      if (vj < bv) { bv = vj; bc = j*64 + lane; }   // j ascending => idx ascending
    }
    #pragma unroll
    for (int off = 32; off; off >>= 1) {
      float ov = __shfl_xor(bv, off);
      int   oc = __shfl_xor(bc, off);
      if (ov < bv || (ov == bv && oc < bc)) { bv = ov; bc = oc; }
    }
    if ((bc & 63) == lane) mask &= ~(1u << (bc >> 6));
    if (lane == 0) out[((size_t)b*16 + r)*Nq + q] = bc;
  }
}

template<int NK>
__global__ __launch_bounds__(256) void knn_glob(const float* __restrict__ cq, int Nq,
                                                const float* __restrict__ ck,
                                                int* __restrict__ out)
{
  __shared__ float smem[4*NK];
  knn_body<NK>(cq, Nq, ck, out, blockIdx.y, blockIdx.x*4, smem);
}

// ---------------------------------------------------------------------------
// FPS (pointnet2 semantics, start idx 0), both levels for one batch per block.
// 256 threads; dists in registers; argmax: per-lane -> wave shfl -> LDS x-wave.
// Ties: first occurrence (smallest point index) — matched via explicit index.
// ---------------------------------------------------------------------------
DI void fps_combine_max(float& bv, int& bp, float ov, int op2)
{
  if (ov > bv || (ov == bv && op2 < bp)) { bv = ov; bp = op2; }
}

__device__ void fps_body(const float* __restrict__ x, int b,
                         int* __restrict__ s1, float* __restrict__ coorq,
                         int* __restrict__ s2, float* __restrict__ coorq2,
                         float* __restrict__ outc, float* smem)
{
  float* xs  = smem;          // 2048
  float* ys  = smem + 2048;
  float* zs  = smem + 4096;
  float* xs2 = smem + 6144;   // 512
  float* ys2 = smem + 6656;
  float* zs2 = smem + 7168;
  int*   sel = (int*)(smem + 7680);   // 512
  float* wv  = smem + 8192;           // [2][4]
  int*   wp  = (int*)(smem + 8200);   // [2][4]
  const int tid = threadIdx.x, lane = tid & 63, w = tid >> 6;

  for (int i = tid; i < 2048; i += 256) {
    xs[i] = x[((size_t)b*3 + 0)*2048 + i];
    ys[i] = x[((size_t)b*3 + 1)*2048 + i];
    zs[i] = x[((size_t)b*3 + 2)*2048 + i];
  }
  __syncthreads();

  float px[8], py[8], pz[8], dl[8];
  #pragma unroll
  for (int j = 0; j < 8; ++j) {
    int p = tid + 256*j;
    px[j] = xs[p]; py[j] = ys[p]; pz[j] = zs[p];
    dl[j] = 1e10f;
  }
  int far = 0;
  for (int i = 0; i < 512; ++i) {
    if (tid == 0) sel[i] = far;
    float cx = xs[far], cy = ys[far], cz = zs[far];
    float bv = -FLT_MAX; int bp = 0x7FFFFFFF;
    #pragma unroll
    for (int j = 0; j < 8; ++j) {
      float dx = f_sub(px[j], cx);
      float dy = f_sub(py[j], cy);
      float dz = f_sub(pz[j], cz);
      float d  = f_add(f_add(f_mul(dx,dx), f_mul(dy,dy)), f_mul(dz,dz));
      float nd = fminf(dl[j], d);
      dl[j] = nd;
      if (nd > bv) { bv = nd; bp = tid + 256*j; }  // j ascending -> idx ascending
    }
    #pragma unroll
    for (int off = 32; off; off >>= 1)
      fps_combine_max(bv, bp, __shfl_xor(bv, off), __shfl_xor(bp, off));
    int par = i & 1;
    if (lane == 0) { wv[par*4 + w] = bv; wp[par*4 + w] = bp; }
    __syncthreads();
    bv = wv[par*4]; bp = wp[par*4];
    #pragma unroll
    for (int ww = 1; ww < 4; ++ww) fps_combine_max(bv, bp, wv[par*4+ww], wp[par*4+ww]);
    far = bp;
  }
  __syncthreads();
  for (int i = tid; i < 512; i += 256) {
    int p = sel[i];
    float a = xs[p], bb = ys[p], c = zs[p];
    xs2[i] = a; ys2[i] = bb; zs2[i] = c;
    s1[b*512 + i] = p;
    coorq[((size_t)b*3 + 0)*512 + i] = a;
    coorq[((size_t)b*3 + 1)*512 + i] = bb;
    coorq[((size_t)b*3 + 2)*512 + i] = c;
  }
  __syncthreads();

  float qx2[2], qy2[2], qz2[2], dl2[2];
  #pragma unroll
  for (int j = 0; j < 2; ++j) {
    int p = tid + 256*j;
    qx2[j] = xs2[p]; qy2[j] = ys2[p]; qz2[j] = zs2[p];
    dl2[j] = 1e10f;
  }
  far = 0;
  for (int i = 0; i < 128; ++i) {
    if (tid == 0) sel[i] = far;
    float cx = xs2[far], cy = ys2[far], cz = zs2[far];
    float bv = -FLT_MAX; int bp = 0x7FFFFFFF;
    #pragma unroll
    for (int j = 0; j < 2; ++j) {
      float dx = f_sub(qx2[j], cx);
      float dy = f_sub(qy2[j], cy);
      float dz = f_sub(qz2[j], cz);
      float d  = f_add(f_add(f_mul(dx,dx), f_mul(dy,dy)), f_mul(dz,dz));
      float nd = fminf(dl2[j], d);
      dl2[j] = nd;
      if (nd > bv) { bv = nd; bp = tid + 256*j; }
    }
    #pragma unroll
    for (int off = 32; off; off >>= 1)
      fps_combine_max(bv, bp, __shfl_xor(bv, off), __shfl_xor(bp, off));
    int par = i & 1;
    if (lane == 0) { wv[par*4 + w] = bv; wp[par*4 + w] = bp; }
    __syncthreads();
    bv = wv[par*4]; bp = wp[par*4];
    #pragma unroll
    for (int ww = 1; ww < 4; ++ww) fps_combine_max(bv, bp, wv[par*4+ww], wp[par*4+ww]);
    far = bp;
  }
  __syncthreads();
  for (int i = tid; i < 128; i += 256) {
    int p = sel[i];
    float a = xs2[p], bb = ys2[p], c = zs2[p];
    s2[b*128 + i] = p;
    coorq2[((size_t)b*3 + 0)*128 + i] = a;
    coorq2[((size_t)b*3 + 1)*128 + i] = bb;
    coorq2[((size_t)b*3 + 2)*128 + i] = c;
    outc[((size_t)b*3 + 0)*128 + i] = a;
    outc[((size_t)b*3 + 1)*128 + i] = bb;
    outc[((size_t)b*3 + 2)*128 + i] = c;
  }
}

// ---------------------------------------------------------------------------
// mega1: blocks 0-7 FPS (long latency chain), 8-71 input_trans, 72+ knn1.
// FPS/in_trans/knn1 are mutually independent -> overlap inside one dispatch.
// ---------------------------------------------------------------------------
__global__ __launch_bounds__(256) void mega1(
    const float* __restrict__ x, const float* __restrict__ w_in, const float* __restrict__ b_in,
    float* __restrict__ f0T, int* __restrict__ idx1,
    int* __restrict__ s1, float* __restrict__ coorq,
    int* __restrict__ s2, float* __restrict__ coorq2, float* __restrict__ outc)
{
  __shared__ float smem[8208];
  const int bid = blockIdx.x;
  if (bid < 8) {
    fps_body(x, bid, s1, coorq, s2, coorq2, outc, smem);
  } else if (bid < 72) {
    int t = (bid - 8)*256 + threadIdx.x;   // (b,n), 16384 total
    int b = t >> 11, n = t & 2047;
    float x0 = x[((size_t)b*3 + 0)*2048 + n];
    float x1 = x[((size_t)b*3 + 1)*2048 + n];
    float x2 = x[((size_t)b*3 + 2)*2048 + n];
    float* op = f0T + (size_t)t*8;
    #pragma unroll
    for (int o = 0; o < 8; ++o)
      op[o] = w_in[o*3+0]*x0 + w_in[o*3+1]*x1 + w_in[o*3+2]*x2 + b_in[o];
  } else {
    int vb = bid - 72;           // 4096 blocks: 512 per batch, 4 queries each
    int b = vb >> 9;
    int qbase = (vb & 511)*4;
    knn_body<2048>(x, 2048, x, idx1, b, qbase, smem);
  }
}

// ---------------------------------------------------------------------------
// Edge conv pass1: y = W * [feat - xq ; xq] with scrambled gather; per-(b,group)
// GroupNorm stats via block reduce + atomicAdd. Optionally stores y.
// Features are stored transposed [B, Ncols, C] so columns are contiguous.
// ---------------------------------------------------------------------------
template<int C, int O, int NQ, int NK, bool STORE>
__global__ __launch_bounds__(256) void conv_p1(
    const float* __restrict__ xqT, int xq_cols, const int* __restrict__ qg,
    const float* __restrict__ xkT, const int* __restrict__ knn_idx,
    const float* __restrict__ w, float* __restrict__ y, float* __restrict__ stats)
{
  constexpr int GRP = O/4;
  const int tid = threadIdx.x;
  const int nt = blockIdx.x, g = blockIdx.y, b = blockIdx.z;
  alignas(16) __shared__ float sxq[16*C];
  alignas(16) __shared__ float sw[GRP*2*C];
  __shared__ float red[8];
  for (int i = tid; i < 16*C; i += 256) {
    int nn = i / C, c = i % C;
    int q = nt*16 + nn;
    int src = qg ? qg[b*NQ + q] : q;
    sxq[i] = xqT[((size_t)b*xq_cols + src)*C + c];
  }
  for (int i = tid; i < GRP*2*C; i += 256)
    sw[i] = w[(size_t)g*GRP*2*C + i];
  __syncthreads();

  const int nloc = tid >> 4, kk = tid & 15;
  const int n = nt*16 + nloc;
  const int flat = n*16 + kk;              // scrambled gather of the source
  const int r = flat / NQ, s = flat % NQ;
  const int nbr = knn_idx[((size_t)b*16 + r)*NQ + s];

  float xqv[C], h1[C];
  {
    const float4* xq4 = (const float4*)(sxq + nloc*C);
    const float4* xk4 = (const float4*)(xkT + ((size_t)b*NK + nbr)*C);
    #pragma unroll
    for (int c4 = 0; c4 < C/4; ++c4) {
      float4 a = xq4[c4], k = xk4[c4];
      xqv[4*c4+0] = a.x; xqv[4*c4+1] = a.y; xqv[4*c4+2] = a.z; xqv[4*c4+3] = a.w;
      h1[4*c4+0] = k.x - a.x; h1[4*c4+1] = k.y - a.y;
      h1[4*c4+2] = k.z - a.z; h1[4*c4+3] = k.w - a.w;
    }
  }
  float lsum = 0.f, lsq = 0.f;
  float* yp = nullptr;
  if constexpr (STORE) yp = y + (((size_t)b*O + (size_t)g*GRP)*NQ + n)*16 + kk;
  for (int o = 0; o < GRP; ++o) {
    const float4* wr = (const float4*)(sw + o*2*C);
    float acc = 0.f;
    #pragma unroll
    for (int c4 = 0; c4 < C/4; ++c4) {
      float4 w4 = wr[c4];
      acc += w4.x*h1[4*c4] + w4.y*h1[4*c4+1] + w4.z*h1[4*c4+2] + w4.w*h1[4*c4+3];
    }
    #pragma unroll
    for (int c4 = 0; c4 < C/4; ++c4) {
      float4 w4 = wr[C/4 + c4];
      acc += w4.x*xqv[4*c4] + w4.y*xqv[4*c4+1] + w4.z*xqv[4*c4+2] + w4.w*xqv[4*c4+3];
    }
    if constexpr (STORE) yp[(size_t)o*NQ*16] = acc;
    lsum += acc; lsq += acc*acc;
  }
  #pragma unroll
  for (int off = 32; off; off >>= 1) {
    lsum += __shfl_xor(lsum, off);
    lsq  += __shfl_xor(lsq, off);
  }
  const int lane = tid & 63, wvid = tid >> 6;
  if (lane == 0) { red[wvid] = lsum; red[4+wvid] = lsq; }
  __syncthreads();
  if (tid == 0) {
    float s0  = (red[0]+red[1]) + (red[2]+red[3]);
    float s1v = (red[4]+red[5]) + (red[6]+red[7]);
    atomicAdd(stats + ((size_t)b*4 + g)*2,     s0);
    atomicAdd(stats + ((size_t)b*4 + g)*2 + 1, s1v);
  }
}

// pass2 for layers 2-4 (reads stored y): normalize + affine + lrelu + max over k.
template<int O, int NQ, bool TOUT>
__global__ __launch_bounds__(256) void conv_p2(
    const float* __restrict__ y, const float* __restrict__ stats,
    const float* __restrict__ gamma, const float* __restrict__ beta,
    float* __restrict__ fout)
{
  int t = blockIdx.x*256 + threadIdx.x;
  if (t >= 8*O*NQ) return;
  int b = t / (O*NQ);
  int rem = t % (O*NQ);
  int o, n;
  if (TOUT) { o = rem % O; n = rem / O; }    // write transposed [B,NQ,O]
  else      { n = rem % NQ; o = rem / NQ; }  // write standard   [B,O,NQ]
  int g = o / (O/4);
  const float cnt = (float)((O/4) * NQ * 16);
  float s0 = stats[((size_t)b*4 + g)*2], s1v = stats[((size_t)b*4 + g)*2 + 1];
  float mu = s0 / cnt;
  float var = fmaxf(s1v / cnt - mu*mu, 0.f);
  float rs = 1.f / sqrtf(var + 1e-5f);
  float ga = gamma[o], be = beta[o];
  const float4* yp = (const float4*)(y + ((((size_t)b*O + o)*NQ) + n)*16);
  float m = -FLT_MAX;
  #pragma unroll
  for (int i = 0; i < 4; ++i) {
    float4 v4 = yp[i];
    float vv[4] = {v4.x, v4.y, v4.z, v4.w};
    #pragma unroll
    for (int j = 0; j < 4; ++j) {
      float a = (vv[j] - mu)*rs*ga + be;
      a = a >= 0.f ? a : 0.2f*a;
      m = fmaxf(m, a);
    }
  }
  fout[t] = m;
}

// Layer-1 pass2: recompute conv (y1 is 33MB; recompute is cheaper than storing).
__global__ __launch_bounds__(256) void l1_pass2(
    const float* __restrict__ f0T, const int* __restrict__ idx1,
    const float* __restrict__ w1, const float* __restrict__ stats,
    const float* __restrict__ g1, const float* __restrict__ be1,
    float* __restrict__ f1T)
{
  alignas(16) __shared__ float sw[512];
  __shared__ float sg[32], sb[32];
  int tid = threadIdx.x;
  for (int i = tid; i < 512; i += 256) sw[i] = w1[i];
  if (tid < 32) { sg[tid] = g1[tid]; sb[tid] = be1[tid]; }
  __syncthreads();
  int t = blockIdx.x*256 + tid;   // (b,n)
  int b = t >> 11, n = t & 2047;
  float mean[4], rstd[4];
  const float cnt = 8.f*2048.f*16.f;
  #pragma unroll
  for (int g = 0; g < 4; ++g) {
    float mu = stats[(b*4+g)*2] / cnt;
    float var = fmaxf(stats[(b*4+g)*2+1]/cnt - mu*mu, 0.f);
    mean[g] = mu; rstd[g] = 1.f/sqrtf(var + 1e-5f);
  }
  const float4* xqp = (const float4*)(f0T + (size_t)t*8);
  float4 q0 = xqp[0], q1 = xqp[1];
  float xq[8] = {q0.x,q0.y,q0.z,q0.w,q1.x,q1.y,q1.z,q1.w};
  float h[16][8];
  #pragma unroll
  for (int kk = 0; kk < 16; ++kk) {
    int flat = n*16 + kk, r = flat >> 11, s = flat & 2047;
    int nbr = idx1[((b*16 + r) << 11) + s];
    const float4* xkp = (const float4*)(f0T + ((size_t)(b << 11) + nbr)*8);
    float4 k0 = xkp[0], k1 = xkp[1];
    h[kk][0]=k0.x-xq[0]; h[kk][1]=k0.y-xq[1]; h[kk][2]=k0.z-xq[2]; h[kk][3]=k0.w-xq[3];
    h[kk][4]=k1.x-xq[4]; h[kk][5]=k1.y-xq[5]; h[kk][6]=k1.z-xq[6]; h[kk][7]=k1.w-xq[7];
  }
  float* op = f1T + (size_t)t*32;
  for (int o = 0; o < 32; ++o) {
    const float4* wp4 = (const float4*)(sw + o*16);
    float4 wa = wp4[0], wb = wp4[1], wc = wp4[2], wd = wp4[3];
    float base = wc.x*xq[0]+wc.y*xq[1]+wc.z*xq[2]+wc.w*xq[3]
               + wd.x*xq[4]+wd.y*xq[5]+wd.z*xq[6]+wd.w*xq[7];
    int g = o >> 3;
    float mu = mean[g], rs = rstd[g], ga = sg[o], be = sb[o];
    float m = -FLT_MAX;
    #pragma unroll
    for (int kk = 0; kk < 16; ++kk) {
      float acc = base
        + wa.x*h[kk][0]+wa.y*h[kk][1]+wa.z*h[kk][2]+wa.w*h[kk][3]
        + wb.x*h[kk][4]+wb.y*h[kk][5]+wb.z*h[kk][6]+wb.w*h[kk][7];
      float a2 = (acc - mu)*rs*ga + be;
      a2 = a2 >= 0.f ? a2 : 0.2f*a2;
      m = fmaxf(m, a2);
    }
    op[o] = m;
  }
}

// ---------------------------------------------------------------------------
extern "C" void kernel_launch(void* const* d_in, const int* in_sizes, int n_in,
                              void* d_out, int out_size, void* d_ws, size_t ws_size,
                              hipStream_t stream)
{
  (void)in_sizes; (void)n_in; (void)out_size; (void)ws_size;
  const float* x    = (const float*)d_in[0];
  const float* w_in = (const float*)d_in[1];
  const float* b_in = (const float*)d_in[2];
  const float* w1   = (const float*)d_in[3];
  const float* g1   = (const float*)d_in[4];
  const float* be1  = (const float*)d_in[5];
  const float* w2   = (const float*)d_in[6];
  const float* g2   = (const float*)d_in[7];
  const float* be2  = (const float*)d_in[8];
  const float* w3   = (const float*)d_in[9];
  const float* g3   = (const float*)d_in[10];
  const float* be3  = (const float*)d_in[11];
  const float* w4   = (const float*)d_in[12];
  const float* g4   = (const float*)d_in[13];
  const float* be4  = (const float*)d_in[14];

  float* ws = (float*)d_ws;
  float* stats  = ws;                         // 256  (4 layers x 8b x 4g x 2)
  float* f0T    = ws + 256;                   // [8,2048,8]
  int*   idx1   = (int*)(ws + 131328);        // [8,16,2048]
  float* f1T    = ws + 393472;                // [8,2048,32]
  int*   s1     = (int*)(ws + 917760);        // [8,512]
  float* coorq  = ws + 921856;                // [8,3,512]
  int*   idx2   = (int*)(ws + 934144);        // [8,16,512]
  float* f2T    = ws + 999680;                // [8,512,64]
  int*   idx3   = (int*)(ws + 1261824);       // [8,16,512]
  float* f3T    = ws + 1327360;               // [8,512,64]
  int*   s2     = (int*)(ws + 1589504);       // [8,128]
  float* coorq2 = ws + 1590528;               // [8,3,128]
  int*   idx4   = (int*)(ws + 1593600);       // [8,16,128]
  float* ybuf   = ws + 1609984;               // up to [8,64,512,16] floats

  float* outc = (float*)d_out;                // [8,3,128]
  float* f4   = (float*)d_out + 3072;         // [8,128,128]

  hipMemsetAsync(stats, 0, 256*sizeof(float), stream);

  // FPS(1+2) + input_trans + knn1, overlapped in one dispatch.
  mega1<<<dim3(8 + 64 + 4096), 256, 0, stream>>>(
      x, w_in, b_in, f0T, idx1, s1, coorq, s2, coorq2, outc);

  // Layer 1 (C=8 -> O=32, Nq=Nk=2048): stats pass (no store) + recompute pass2.
  conv_p1<8, 32, 2048, 2048, false><<<dim3(128, 4, 8), 256, 0, stream>>>(
      f0T, 2048, nullptr, f0T, idx1, w1, nullptr, stats);
  l1_pass2<<<64, 256, 0, stream>>>(f0T, idx1, w1, stats, g1, be1, f1T);

  // Layer 2 (C=32 -> O=64, Nq=512, Nk=2048), x_q gathered by s1.
  knn_glob<2048><<<dim3(128, 8), 256, 0, stream>>>(coorq, 512, x, idx2);
  conv_p1<32, 64, 512, 2048, true><<<dim3(32, 4, 8), 256, 0, stream>>>(
      f1T, 2048, s1, f1T, idx2, w2, ybuf, stats + 64);
  conv_p2<64, 512, true><<<1024, 256, 0, stream>>>(ybuf, stats + 64, g2, be2, f2T);

  // Layer 3 (C=64 -> O=64, Nq=Nk=512).
  knn_glob<512><<<dim3(128, 8), 256, 0, stream>>>(coorq, 512, coorq, idx3);
  conv_p1<64, 64, 512, 512, true><<<dim3(32, 4, 8), 256, 0, stream>>>(
      f2T, 512, nullptr, f2T, idx3, w3, ybuf, stats + 128);
  conv_p2<64, 512, true><<<1024, 256, 0, stream>>>(ybuf, stats + 128, g3, be3, f3T);

  // Layer 4 (C=64 -> O=128, Nq=128, Nk=512), x_q gathered by s2.
  knn_glob<512><<<dim3(32, 8), 256, 0, stream>>>(coorq2, 128, coorq, idx4);
  conv_p1<64, 128, 128, 512, true><<<dim3(8, 4, 8), 256, 0, stream>>>(
      f3T, 512, s2, f3T, idx4, w4, ybuf, stats + 192);
  conv_p2<128, 128, false><<<512, 256, 0, stream>>>(ybuf, stats + 192, g4, be4, f4);
}

// Round 2
// 570.790 us; speedup vs baseline: 1.6227x; 1.6227x over previous
//
#include <hip/hip_runtime.h>
#include <float.h>
#include <stdint.h>

// DGCNN_Grouper forward on MI355X. B=8, N=2048, K=16, fp32.

#define DI __device__ __forceinline__
DI float f_add(float a, float b) { return __fadd_rn(a, b); }
DI float f_sub(float a, float b) { return __fsub_rn(a, b); }
DI float f_mul(float a, float b) { return __fmul_rn(a, b); }

DI uint64_t umax64(uint64_t a, uint64_t b) { return a > b ? a : b; }

// 6-step gfx9 DPP max-reduce over 64 lanes of a packed u64 key; returns the
// wave max broadcast to all lanes (via readlane 63). Identity 0 is safe:
// real keys are always nonzero (low 32 bits = ~idx, idx < 2048).
template<int CTRL, int RMASK>
DI uint64_t dpp_step_max(uint64_t k) {
  uint32_t lo = (uint32_t)__builtin_amdgcn_update_dpp(0, (int)(uint32_t)k,        CTRL, RMASK, 0xF, false);
  uint32_t hi = (uint32_t)__builtin_amdgcn_update_dpp(0, (int)(uint32_t)(k >> 32), CTRL, RMASK, 0xF, false);
  uint64_t o = ((uint64_t)hi << 32) | lo;
  return umax64(k, o);
}
DI uint64_t wave_max_bcast(uint64_t k) {
  k = dpp_step_max<0x111, 0xF>(k);  // row_shr:1
  k = dpp_step_max<0x112, 0xF>(k);  // row_shr:2
  k = dpp_step_max<0x114, 0xF>(k);  // row_shr:4
  k = dpp_step_max<0x118, 0xF>(k);  // row_shr:8
  k = dpp_step_max<0x142, 0xA>(k);  // row_bcast15 -> rows 1,3
  k = dpp_step_max<0x143, 0xC>(k);  // row_bcast31 -> rows 2,3
  uint32_t lo = (uint32_t)__builtin_amdgcn_readlane((int)(uint32_t)k, 63);
  uint32_t hi = (uint32_t)__builtin_amdgcn_readlane((int)(uint32_t)(k >> 32), 63);
  return ((uint64_t)hi << 32) | lo;
}

// ---------------------------------------------------------------------------
// kNN (unchanged numerics from the passing round-1 kernel).
// ---------------------------------------------------------------------------
template<int NK>
DI void knn_body(const float* __restrict__ cq, int Nq,
                 const float* __restrict__ ck, int* __restrict__ out,
                 int b, int qbase, float* smem)
{
  constexpr int CPL = NK / 64;
  float* xs = smem;
  float* ys = smem + NK;
  float* zs = smem + 2*NK;
  float* rr = smem + 3*NK;
  const int tid = threadIdx.x;
  for (int i = tid; i < NK; i += 256) {
    float a  = ck[((size_t)b*3 + 0)*NK + i];
    float bb = ck[((size_t)b*3 + 1)*NK + i];
    float c  = ck[((size_t)b*3 + 2)*NK + i];
    xs[i] = a; ys[i] = bb; zs[i] = c;
    rr[i] = f_add(f_add(f_mul(a,a), f_mul(bb,bb)), f_mul(c,c));
  }
  __syncthreads();
  const int lane = tid & 63, w = tid >> 6;
  const int q = qbase + w;
  if (q >= Nq) return;
  float qx = cq[((size_t)b*3 + 0)*Nq + q];
  float qy = cq[((size_t)b*3 + 1)*Nq + q];
  float qz = cq[((size_t)b*3 + 2)*Nq + q];
  float qq = f_add(f_add(f_mul(qx,qx), f_mul(qy,qy)), f_mul(qz,qz));
  float v[CPL];
  #pragma unroll
  for (int j = 0; j < CPL; ++j) {
    int c = j*64 + lane;
    float dot = f_add(f_add(f_mul(qx,xs[c]), f_mul(qy,ys[c])), f_mul(qz,zs[c]));
    v[j] = f_sub(f_add(qq, rr[c]), f_mul(2.0f, dot));
  }
  unsigned mask = (CPL >= 32) ? 0xFFFFFFFFu : ((1u << CPL) - 1u);
  for (int r = 0; r < 16; ++r) {
    float bv = FLT_MAX; int bc = 0x7FFFFFFF;
    #pragma unroll
    for (int j = 0; j < CPL; ++j) {
      float vj = ((mask >> j) & 1u) ? v[j] : FLT_MAX;
      if (vj < bv) { bv = vj; bc = j*64 + lane; }
    }
    #pragma unroll
    for (int off = 32; off; off >>= 1) {
      float ov = __shfl_xor(bv, off);
      int   oc = __shfl_xor(bc, off);
      if (ov < bv || (ov == bv && oc < bc)) { bv = ov; bc = oc; }
    }
    if ((bc & 63) == lane) mask &= ~(1u << (bc >> 6));
    if (lane == 0) out[((size_t)b*16 + r)*Nq + q] = bc;
  }
}

// ---------------------------------------------------------------------------
// FPS with packed-key DPP argmax. Level 1: 4 waves, 8 pts/lane, one barrier
// per iteration. Level 2: single wave, no barriers in the loop.
// Distance arithmetic is bit-identical to the reference (rn ops, fminf).
// ---------------------------------------------------------------------------
__device__ void fps_body(const float* __restrict__ x, int b,
                         int* __restrict__ s1, float* __restrict__ coorq,
                         int* __restrict__ s2, float* __restrict__ coorq2,
                         float* __restrict__ outc, char* smem_raw)
{
  float4*   pts   = (float4*)smem_raw;                      // [2048] (level2 reuses [0..511])
  int*      sel   = (int*)(smem_raw + 32768);               // [512]
  uint64_t* wkeys = (uint64_t*)(smem_raw + 32768 + 2048);   // [2][4]
  const int tid = threadIdx.x, lane = tid & 63, w = tid >> 6;

  for (int i = tid; i < 2048; i += 256)
    pts[i] = make_float4(x[((size_t)b*3 + 0)*2048 + i],
                         x[((size_t)b*3 + 1)*2048 + i],
                         x[((size_t)b*3 + 2)*2048 + i], 0.f);
  __syncthreads();

  float px[8], py[8], pz[8], dl[8];
  #pragma unroll
  for (int j = 0; j < 8; ++j) {
    float4 p = pts[tid + 256*j];
    px[j] = p.x; py[j] = p.y; pz[j] = p.z; dl[j] = 1e10f;
  }

  int far = 0;
  for (int i = 0; i < 512; ++i) {
    if (tid == 0) sel[i] = far;
    float4 c = pts[far];
    uint64_t k[8];
    #pragma unroll
    for (int j = 0; j < 8; ++j) {
      float dx = f_sub(px[j], c.x);
      float dy = f_sub(py[j], c.y);
      float dz = f_sub(pz[j], c.z);
      float d  = f_add(f_add(f_mul(dx,dx), f_mul(dy,dy)), f_mul(dz,dz));
      float nd = fminf(dl[j], d);
      dl[j] = nd;
      k[j] = ((uint64_t)__float_as_uint(nd) << 32) | (uint32_t)~(uint32_t)(tid + 256*j);
    }
    uint64_t a0 = umax64(k[0], k[1]), a1 = umax64(k[2], k[3]);
    uint64_t a2 = umax64(k[4], k[5]), a3 = umax64(k[6], k[7]);
    uint64_t kk = umax64(umax64(a0, a1), umax64(a2, a3));
    kk = wave_max_bcast(kk);
    if (lane == 0) wkeys[(i & 1)*4 + w] = kk;
    __syncthreads();
    const uint64_t* wk = wkeys + (i & 1)*4;
    uint64_t g = umax64(umax64(wk[0], wk[1]), umax64(wk[2], wk[3]));
    far = (int)~(uint32_t)g;
  }
  __syncthreads();

  // Dump level 1 + register-bounce the 512 selected points into pts[0..511].
  int p0 = sel[tid], p1 = sel[tid + 256];
  float4 v0 = pts[p0], v1 = pts[p1];
  s1[b*512 + tid]       = p0;
  s1[b*512 + tid + 256] = p1;
  coorq[((size_t)b*3 + 0)*512 + tid] = v0.x;
  coorq[((size_t)b*3 + 1)*512 + tid] = v0.y;
  coorq[((size_t)b*3 + 2)*512 + tid] = v0.z;
  coorq[((size_t)b*3 + 0)*512 + tid + 256] = v1.x;
  coorq[((size_t)b*3 + 1)*512 + tid + 256] = v1.y;
  coorq[((size_t)b*3 + 2)*512 + tid + 256] = v1.z;
  __syncthreads();
  pts[tid] = v0; pts[tid + 256] = v1;
  __syncthreads();

  // Level 2: 512 -> 128, single wave (w==0), 8 pts/lane, no barriers inside.
  if (w == 0) {
    float qx[8], qy[8], qz[8], d2[8];
    #pragma unroll
    for (int j = 0; j < 8; ++j) {
      float4 p = pts[lane + 64*j];
      qx[j] = p.x; qy[j] = p.y; qz[j] = p.z; d2[j] = 1e10f;
    }
    int far2 = 0;
    for (int i = 0; i < 128; ++i) {
      if (lane == 0) sel[i] = far2;
      float4 c = pts[far2];
      uint64_t k[8];
      #pragma unroll
      for (int j = 0; j < 8; ++j) {
        float dx = f_sub(qx[j], c.x);
        float dy = f_sub(qy[j], c.y);
        float dz = f_sub(qz[j], c.z);
        float d  = f_add(f_add(f_mul(dx,dx), f_mul(dy,dy)), f_mul(dz,dz));
        float nd = fminf(d2[j], d);
        d2[j] = nd;
        k[j] = ((uint64_t)__float_as_uint(nd) << 32) | (uint32_t)~(uint32_t)(lane + 64*j);
      }
      uint64_t a0 = umax64(k[0], k[1]), a1 = umax64(k[2], k[3]);
      uint64_t a2 = umax64(k[4], k[5]), a3 = umax64(k[6], k[7]);
      uint64_t kk = umax64(umax64(a0, a1), umax64(a2, a3));
      kk = wave_max_bcast(kk);
      far2 = (int)~(uint32_t)kk;
    }
  }
  __syncthreads();
  if (tid < 128) {
    int p = sel[tid];
    float4 v = pts[p];
    s2[b*128 + tid] = p;
    coorq2[((size_t)b*3 + 0)*128 + tid] = v.x;
    coorq2[((size_t)b*3 + 1)*128 + tid] = v.y;
    coorq2[((size_t)b*3 + 2)*128 + tid] = v.z;
    outc[((size_t)b*3 + 0)*128 + tid] = v.x;
    outc[((size_t)b*3 + 1)*128 + tid] = v.y;
    outc[((size_t)b*3 + 2)*128 + tid] = v.z;
  }
}

// ---------------------------------------------------------------------------
// mega1: blocks 0-7 FPS, 8-71 input_trans, 72+ knn1. Mutually independent.
// ---------------------------------------------------------------------------
__global__ __launch_bounds__(256) void mega1(
    const float* __restrict__ x, const float* __restrict__ w_in, const float* __restrict__ b_in,
    float* __restrict__ f0T, int* __restrict__ idx1,
    int* __restrict__ s1, float* __restrict__ coorq,
    int* __restrict__ s2, float* __restrict__ coorq2, float* __restrict__ outc)
{
  __shared__ char smem_raw[34880] __attribute__((aligned(16)));
  const int bid = blockIdx.x;
  if (bid < 8) {
    fps_body(x, bid, s1, coorq, s2, coorq2, outc, smem_raw);
  } else if (bid < 72) {
    int t = (bid - 8)*256 + threadIdx.x;
    int b = t >> 11, n = t & 2047;
    float x0 = x[((size_t)b*3 + 0)*2048 + n];
    float x1 = x[((size_t)b*3 + 1)*2048 + n];
    float x2 = x[((size_t)b*3 + 2)*2048 + n];
    float* op = f0T + (size_t)t*8;
    #pragma unroll
    for (int o = 0; o < 8; ++o)
      op[o] = w_in[o*3+0]*x0 + w_in[o*3+1]*x1 + w_in[o*3+2]*x2 + b_in[o];
  } else {
    int vb = bid - 72;
    int b = vb >> 9;
    int qbase = (vb & 511)*4;
    knn_body<2048>(x, 2048, x, idx1, b, qbase, (float*)smem_raw);
  }
}

// ---------------------------------------------------------------------------
// Edge conv pass1 body (unchanged numerics): y = W*[feat-xq; xq], GN stats.
// ---------------------------------------------------------------------------
template<int C, int O, int NQ, int NK, bool STORE>
DI void conv_p1_body(
    const float* __restrict__ xqT, int xq_cols, const int* __restrict__ qg,
    const float* __restrict__ xkT, const int* __restrict__ knn_idx,
    const float* __restrict__ w, float* __restrict__ y, float* __restrict__ stats,
    int nt, int g, int b, float* smem)
{
  constexpr int GRP = O/4;
  const int tid = threadIdx.x;
  float* sxq = smem;
  float* sw  = smem + 16*C;
  float* red = sw + GRP*2*C;
  for (int i = tid; i < 16*C; i += 256) {
    int nn = i / C, c = i % C;
    int q = nt*16 + nn;
    int src = qg ? qg[b*NQ + q] : q;
    sxq[i] = xqT[((size_t)b*xq_cols + src)*C + c];
  }
  for (int i = tid; i < GRP*2*C; i += 256)
    sw[i] = w[(size_t)g*GRP*2*C + i];
  __syncthreads();

  const int nloc = tid >> 4, kk = tid & 15;
  const int n = nt*16 + nloc;
  const int flat = n*16 + kk;
  const int r = flat / NQ, s = flat % NQ;
  const int nbr = knn_idx[((size_t)b*16 + r)*NQ + s];

  float xqv[C], h1[C];
  {
    const float4* xq4 = (const float4*)(sxq + nloc*C);
    const float4* xk4 = (const float4*)(xkT + ((size_t)b*NK + nbr)*C);
    #pragma unroll
    for (int c4 = 0; c4 < C/4; ++c4) {
      float4 a = xq4[c4], k = xk4[c4];
      xqv[4*c4+0] = a.x; xqv[4*c4+1] = a.y; xqv[4*c4+2] = a.z; xqv[4*c4+3] = a.w;
      h1[4*c4+0] = k.x - a.x; h1[4*c4+1] = k.y - a.y;
      h1[4*c4+2] = k.z - a.z; h1[4*c4+3] = k.w - a.w;
    }
  }
  float lsum = 0.f, lsq = 0.f;
  float* yp = nullptr;
  if constexpr (STORE) yp = y + (((size_t)b*O + (size_t)g*GRP)*NQ + n)*16 + kk;
  for (int o = 0; o < GRP; ++o) {
    const float4* wr = (const float4*)(sw + o*2*C);
    float acc = 0.f;
    #pragma unroll
    for (int c4 = 0; c4 < C/4; ++c4) {
      float4 w4 = wr[c4];
      acc += w4.x*h1[4*c4] + w4.y*h1[4*c4+1] + w4.z*h1[4*c4+2] + w4.w*h1[4*c4+3];
    }
    #pragma unroll
    for (int c4 = 0; c4 < C/4; ++c4) {
      float4 w4 = wr[C/4 + c4];
      acc += w4.x*xqv[4*c4] + w4.y*xqv[4*c4+1] + w4.z*xqv[4*c4+2] + w4.w*xqv[4*c4+3];
    }
    if constexpr (STORE) yp[(size_t)o*NQ*16] = acc;
    lsum += acc; lsq += acc*acc;
  }
  #pragma unroll
  for (int off = 32; off; off >>= 1) {
    lsum += __shfl_xor(lsum, off);
    lsq  += __shfl_xor(lsq, off);
  }
  const int lane = tid & 63, wvid = tid >> 6;
  if (lane == 0) { red[wvid] = lsum; red[4+wvid] = lsq; }
  __syncthreads();
  if (tid == 0) {
    float s0  = (red[0]+red[1]) + (red[2]+red[3]);
    float s1v = (red[4]+red[5]) + (red[6]+red[7]);
    atomicAdd(stats + ((size_t)b*4 + g)*2,     s0);
    atomicAdd(stats + ((size_t)b*4 + g)*2 + 1, s1v);
  }
}

template<int C, int O, int NQ, int NK, bool STORE>
__global__ __launch_bounds__(256) void conv_p1(
    const float* __restrict__ xqT, int xq_cols, const int* __restrict__ qg,
    const float* __restrict__ xkT, const int* __restrict__ knn_idx,
    const float* __restrict__ w, float* __restrict__ y, float* __restrict__ stats)
{
  __shared__ float smem_f[16*C + (O/4)*2*C + 8];
  conv_p1_body<C, O, NQ, NK, STORE>(xqT, xq_cols, qg, xkT, knn_idx, w, y, stats,
                                    blockIdx.x, blockIdx.y, blockIdx.z, smem_f);
}

// ---------------------------------------------------------------------------
// mega2: knn2 + conv_p1(L1 stats) + knn3 + knn4 in one dispatch (all depend
// only on mega1 outputs, mutually independent).
// ---------------------------------------------------------------------------
__global__ __launch_bounds__(256) void mega2(
    const float* __restrict__ f0T, const int* __restrict__ idx1,
    const float* __restrict__ w1, float* __restrict__ stats,
    const float* __restrict__ x, const float* __restrict__ coorq,
    const float* __restrict__ coorq2,
    int* __restrict__ idx2, int* __restrict__ idx3, int* __restrict__ idx4)
{
  __shared__ char smem_raw[32768] __attribute__((aligned(16)));
  const int bid = blockIdx.x;
  if (bid < 1024) {
    knn_body<2048>(coorq, 512, x, idx2, bid >> 7, (bid & 127)*4, (float*)smem_raw);
  } else if (bid < 5120) {
    int f = bid - 1024;
    conv_p1_body<8, 32, 2048, 2048, false>(f0T, 2048, nullptr, f0T, idx1, w1,
                                           nullptr, stats,
                                           f & 127, (f >> 7) & 3, f >> 9,
                                           (float*)smem_raw);
  } else if (bid < 6144) {
    int v = bid - 5120;
    knn_body<512>(coorq, 512, coorq, idx3, v >> 7, (v & 127)*4, (float*)smem_raw);
  } else {
    int v = bid - 6144;
    knn_body<512>(coorq2, 128, coorq, idx4, v >> 5, (v & 31)*4, (float*)smem_raw);
  }
}

// pass2 for layers 2-4.
template<int O, int NQ, bool TOUT>
__global__ __launch_bounds__(256) void conv_p2(
    const float* __restrict__ y, const float* __restrict__ stats,
    const float* __restrict__ gamma, const float* __restrict__ beta,
    float* __restrict__ fout)
{
  int t = blockIdx.x*256 + threadIdx.x;
  if (t >= 8*O*NQ) return;
  int b = t / (O*NQ);
  int rem = t % (O*NQ);
  int o, n;
  if (TOUT) { o = rem % O; n = rem / O; }
  else      { n = rem % NQ; o = rem / NQ; }
  int g = o / (O/4);
  const float cnt = (float)((O/4) * NQ * 16);
  float s0 = stats[((size_t)b*4 + g)*2], s1v = stats[((size_t)b*4 + g)*2 + 1];
  float mu = s0 / cnt;
  float var = fmaxf(s1v / cnt - mu*mu, 0.f);
  float rs = 1.f / sqrtf(var + 1e-5f);
  float ga = gamma[o], be = beta[o];
  const float4* yp = (const float4*)(y + ((((size_t)b*O + o)*NQ) + n)*16);
  float m = -FLT_MAX;
  #pragma unroll
  for (int i = 0; i < 4; ++i) {
    float4 v4 = yp[i];
    float vv[4] = {v4.x, v4.y, v4.z, v4.w};
    #pragma unroll
    for (int j = 0; j < 4; ++j) {
      float a = (vv[j] - mu)*rs*ga + be;
      a = a >= 0.f ? a : 0.2f*a;
      m = fmaxf(m, a);
    }
  }
  fout[t] = m;
}

// Layer-1 pass2: recompute conv + GN + lrelu + max.
__global__ __launch_bounds__(256) void l1_pass2(
    const float* __restrict__ f0T, const int* __restrict__ idx1,
    const float* __restrict__ w1, const float* __restrict__ stats,
    const float* __restrict__ g1, const float* __restrict__ be1,
    float* __restrict__ f1T)
{
  alignas(16) __shared__ float sw[512];
  __shared__ float sg[32], sb[32];
  int tid = threadIdx.x;
  for (int i = tid; i < 512; i += 256) sw[i] = w1[i];
  if (tid < 32) { sg[tid] = g1[tid]; sb[tid] = be1[tid]; }
  __syncthreads();
  int t = blockIdx.x*256 + tid;
  int b = t >> 11, n = t & 2047;
  float mean[4], rstd[4];
  const float cnt = 8.f*2048.f*16.f;
  #pragma unroll
  for (int g = 0; g < 4; ++g) {
    float mu = stats[(b*4+g)*2] / cnt;
    float var = fmaxf(stats[(b*4+g)*2+1]/cnt - mu*mu, 0.f);
    mean[g] = mu; rstd[g] = 1.f/sqrtf(var + 1e-5f);
  }
  const float4* xqp = (const float4*)(f0T + (size_t)t*8);
  float4 q0 = xqp[0], q1 = xqp[1];
  float xq[8] = {q0.x,q0.y,q0.z,q0.w,q1.x,q1.y,q1.z,q1.w};
  float h[16][8];
  #pragma unroll
  for (int kk = 0; kk < 16; ++kk) {
    int flat = n*16 + kk, r = flat >> 11, s = flat & 2047;
    int nbr = idx1[((b*16 + r) << 11) + s];
    const float4* xkp = (const float4*)(f0T + ((size_t)(b << 11) + nbr)*8);
    float4 k0 = xkp[0], k1 = xkp[1];
    h[kk][0]=k0.x-xq[0]; h[kk][1]=k0.y-xq[1]; h[kk][2]=k0.z-xq[2]; h[kk][3]=k0.w-xq[3];
    h[kk][4]=k1.x-xq[4]; h[kk][5]=k1.y-xq[5]; h[kk][6]=k1.z-xq[6]; h[kk][7]=k1.w-xq[7];
  }
  float* op = f1T + (size_t)t*32;
  for (int o = 0; o < 32; ++o) {
    const float4* wp4 = (const float4*)(sw + o*16);
    float4 wa = wp4[0], wb = wp4[1], wc = wp4[2], wd = wp4[3];
    float base = wc.x*xq[0]+wc.y*xq[1]+wc.z*xq[2]+wc.w*xq[3]
               + wd.x*xq[4]+wd.y*xq[5]+wd.z*xq[6]+wd.w*xq[7];
    int g = o >> 3;
    float mu = mean[g], rs = rstd[g], ga = sg[o], be = sb[o];
    float m = -FLT_MAX;
    #pragma unroll
    for (int kk = 0; kk < 16; ++kk) {
      float acc = base
        + wa.x*h[kk][0]+wa.y*h[kk][1]+wa.z*h[kk][2]+wa.w*h[kk][3]
        + wb.x*h[kk][4]+wb.y*h[kk][5]+wb.z*h[kk][6]+wb.w*h[kk][7];
      float a2 = (acc - mu)*rs*ga + be;
      a2 = a2 >= 0.f ? a2 : 0.2f*a2;
      m = fmaxf(m, a2);
    }
    op[o] = m;
  }
}

// ---------------------------------------------------------------------------
extern "C" void kernel_launch(void* const* d_in, const int* in_sizes, int n_in,
                              void* d_out, int out_size, void* d_ws, size_t ws_size,
                              hipStream_t stream)
{
  (void)in_sizes; (void)n_in; (void)out_size; (void)ws_size;
  const float* x    = (const float*)d_in[0];
  const float* w_in = (const float*)d_in[1];
  const float* b_in = (const float*)d_in[2];
  const float* w1   = (const float*)d_in[3];
  const float* g1   = (const float*)d_in[4];
  const float* be1  = (const float*)d_in[5];
  const float* w2   = (const float*)d_in[6];
  const float* g2   = (const float*)d_in[7];
  const float* be2  = (const float*)d_in[8];
  const float* w3   = (const float*)d_in[9];
  const float* g3   = (const float*)d_in[10];
  const float* be3  = (const float*)d_in[11];
  const float* w4   = (const float*)d_in[12];
  const float* g4   = (const float*)d_in[13];
  const float* be4  = (const float*)d_in[14];

  float* ws = (float*)d_ws;
  float* stats  = ws;                         // 256
  float* f0T    = ws + 256;                   // [8,2048,8]
  int*   idx1   = (int*)(ws + 131328);        // [8,16,2048]
  float* f1T    = ws + 393472;                // [8,2048,32]
  int*   s1     = (int*)(ws + 917760);        // [8,512]
  float* coorq  = ws + 921856;                // [8,3,512]
  int*   idx2   = (int*)(ws + 934144);        // [8,16,512]
  float* f2T    = ws + 999680;                // [8,512,64]
  int*   idx3   = (int*)(ws + 1261824);       // [8,16,512]
  float* f3T    = ws + 1327360;               // [8,512,64]
  int*   s2     = (int*)(ws + 1589504);       // [8,128]
  float* coorq2 = ws + 1590528;               // [8,3,128]
  int*   idx4   = (int*)(ws + 1593600);       // [8,16,128]
  float* ybuf   = ws + 1609984;               // up to [8,64,512,16]

  float* outc = (float*)d_out;                // [8,3,128]
  float* f4   = (float*)d_out + 3072;         // [8,128,128]

  hipMemsetAsync(stats, 0, 256*sizeof(float), stream);

  // FPS(1+2) + input_trans + knn1.
  mega1<<<dim3(8 + 64 + 4096), 256, 0, stream>>>(
      x, w_in, b_in, f0T, idx1, s1, coorq, s2, coorq2, outc);

  // knn2 + L1 stats + knn3 + knn4.
  mega2<<<dim3(6400), 256, 0, stream>>>(
      f0T, idx1, w1, stats, x, coorq, coorq2, idx2, idx3, idx4);

  // Layer 1 finish.
  l1_pass2<<<64, 256, 0, stream>>>(f0T, idx1, w1, stats, g1, be1, f1T);

  // Layer 2 (C=32 -> O=64, Nq=512, Nk=2048), x_q gathered by s1.
  conv_p1<32, 64, 512, 2048, true><<<dim3(32, 4, 8), 256, 0, stream>>>(
      f1T, 2048, s1, f1T, idx2, w2, ybuf, stats + 64);
  conv_p2<64, 512, true><<<1024, 256, 0, stream>>>(ybuf, stats + 64, g2, be2, f2T);

  // Layer 3 (C=64 -> O=64, Nq=Nk=512).
  conv_p1<64, 64, 512, 512, true><<<dim3(32, 4, 8), 256, 0, stream>>>(
      f2T, 512, nullptr, f2T, idx3, w3, ybuf, stats + 128);
  conv_p2<64, 512, true><<<1024, 256, 0, stream>>>(ybuf, stats + 128, g3, be3, f3T);

  // Layer 4 (C=64 -> O=128, Nq=128, Nk=512), x_q gathered by s2.
  conv_p1<64, 128, 128, 512, true><<<dim3(8, 4, 8), 256, 0, stream>>>(
      f3T, 512, s2, f3T, idx4, w4, ybuf, stats + 192);
  conv_p2<128, 128, false><<<512, 256, 0, stream>>>(ybuf, stats + 192, g4, be4, f4);
}